// Round 8
// baseline (170.521 us; speedup 1.0000x reference)
//
#include <hip/hip_runtime.h>

using v4f = float __attribute__((ext_vector_type(4)));

constexpr int NTOK = 32768;       // 16 * 2048 tokens
constexpr int DIMS = 64;
constexpr int KCODES = 1000;
constexpr int NSPLIT = 4;         // 250 codes per split: 25 groups of 10, zero padding
constexpr int CPSPLIT = 250;
constexpr int GRP = 10;
constexpr float BIG = 3.4e38f;

// ---------------------------------------------------------------- main argmin
// lane = token, x in swizzled LDS (1 ds_read_b128 per lane per d4 per 10-code group),
// e wave-uniform -> scalar loads, per-lane scalar argmin. Per-lane state: acc[10] only.
__global__ __launch_bounds__(256, 2) void vq_main(
    const float* __restrict__ x, const float* __restrict__ emb,
    float* __restrict__ pval, int* __restrict__ pidx,
    float* __restrict__ loss_accum, int* __restrict__ usage)
{
    __shared__ float xs[256 * DIMS];   // 64 KB, swizzled: word = t*64 + (d0 ^ ((t&7)<<2))
    __shared__ float ns[CPSPLIT];      // norms for this split's codes

    const int tid   = threadIdx.x;
    const int split = blockIdx.x >> 7;     // 0..3; bid & 127 fixed across splits -> same x-tile, same XCD (mod 8)
    const int tblk  = blockIdx.x & 127;
    const int tok0  = tblk * 256;          // 256-token tile never crosses a b-boundary
    const int b     = tok0 >> 11;
    const int l0    = tok0 & 2047;
    const int cbase = split * CPSPLIT;
    const float* xgb = x + ((size_t)b << 17) + l0;   // x[b][d][l0+t] = xgb[d*2048 + t]

    // zero-init scratch consumed by vq_output (ws poisoned 0xAA each launch) — r6-proven
    if (blockIdx.x == 0) {
        for (int u = tid; u < KCODES; u += 256) usage[u] = 0;
        if (tid == 0) *loss_accum = 0.f;
    }

    // ---- stage x tile: thread t owns token t. Global reads coalesced (lanes = consecutive t);
    //      swizzled b128 LDS writes (8 lanes span all 32 banks -> throughput-optimal).
    {
        const int sw = (tid & 7) << 2;
        #pragma unroll
        for (int d4 = 0; d4 < 16; ++d4) {
            v4f v;
            #pragma unroll
            for (int k = 0; k < 4; ++k) v[k] = xgb[(size_t)(d4 * 4 + k) * 2048 + tid];
            *reinterpret_cast<v4f*>(&xs[tid * DIMS + ((d4 * 4) ^ sw)]) = v;
        }
    }

    // ---- norms for this split's 250 codes (validated fp ordering: per-16 FMA nest, pairwise combine)
    if (tid < CPSPLIT) {
        const float* e = emb + (size_t)(cbase + tid) * DIMS;
        float sq[4];
        #pragma unroll
        for (int q = 0; q < 4; ++q) {
            float s = 0.f;
            #pragma unroll
            for (int i = 0; i < 4; ++i) {
                v4f v = *reinterpret_cast<const v4f*>(e + q * 16 + i * 4);
                s = fmaf(v[0], v[0], fmaf(v[1], v[1], fmaf(v[2], v[2], fmaf(v[3], v[3], s))));
            }
            sq[q] = s;
        }
        ns[tid] = (sq[0] + sq[1]) + (sq[2] + sq[3]);
    }

    __syncthreads();

    // ---- 16 read addresses, computed once, static-indexed (reused by all 25 groups)
    const float* xptr[16];
    {
        const int sw = (tid & 7) << 2;
        #pragma unroll
        for (int d4 = 0; d4 < 16; ++d4)
            xptr[d4] = &xs[tid * DIMS + ((d4 * 4) ^ sw)];
    }

    float minv = BIG;
    int   mini = 0;

    for (int g = 0; g < CPSPLIT / GRP; ++g) {        // 25 groups of 10 codes, no tail
        const int c0 = cbase + g * GRP;
        const float* eg = emb + (size_t)c0 * DIMS;

        float acc[GRP];
        #pragma unroll
        for (int c = 0; c < GRP; ++c) acc[c] = 0.f;

        #pragma unroll
        for (int d4 = 0; d4 < 16; ++d4) {
            v4f xq = *reinterpret_cast<const v4f*>(xptr[d4]);   // 1 ds_read_b128, conflict-free
            #pragma unroll
            for (int c = 0; c < GRP; ++c) {
                v4f ev = *reinterpret_cast<const v4f*>(eg + c * DIMS + d4 * 4);  // uniform -> s_load
                #pragma unroll
                for (int k = 0; k < 4; ++k)
                    acc[c] = fmaf(xq[k], ev[k], acc[c]);
            }
        }

        #pragma unroll
        for (int c = 0; c < GRP; ++c) {              // ascending c: strict < keeps first min
            float dist = fmaf(-2.f, acc[c], ns[g * GRP + c]);   // uniform LDS read: broadcast
            if (dist < minv) { minv = dist; mini = c0 + c; }
        }
    }

    const int token = tok0 + tid;
    pval[split * NTOK + token] = minv;               // coalesced
    pidx[split * NTOK + token] = mini;
}

// ---------------------------------------------------------------- merge + gather + STE + loss + usage
// 2D: block = 64 tokens x 4 dim-groups, 512 blocks (r6-proven)
__global__ __launch_bounds__(256) void vq_output(
    const float* __restrict__ x, const float* __restrict__ emb,
    const float* __restrict__ pval, const int* __restrict__ pidx,
    float* __restrict__ out, float* __restrict__ idx_f,
    float* __restrict__ loss_accum, int* __restrict__ usage)
{
    const int tid   = threadIdx.x;
    const int ll    = tid & 63;
    const int dg    = tid >> 6;
    const int token = blockIdx.x * 64 + ll;

    float bv = pval[token];
    int   bi = pidx[token];
    #pragma unroll
    for (int s = 1; s < NSPLIT; ++s) {     // ascending split: strict < keeps lowest idx
        float v  = pval[s * NTOK + token];
        int   i2 = pidx[s * NTOK + token];
        if (v < bv) { bv = v; bi = i2; }
    }
    if (dg == 0) {
        idx_f[token] = (float)bi;
        atomicOr(&usage[bi], 1);           // device-scope atomic: XCD-safe
    }

    const int b = token >> 11, l = token & 2047;
    const float* xb = x   + ((size_t)b << 17) + l + (size_t)(dg * 16) * 2048;
    float*       ob = out + ((size_t)b << 17) + l + (size_t)(dg * 16) * 2048;
    const float* e  = emb + (size_t)bi * DIMS + dg * 16;

    float lsum = 0.f;
    #pragma unroll
    for (int q4 = 0; q4 < 4; ++q4) {
        v4f q = *reinterpret_cast<const v4f*>(e + q4 * 4);
        #pragma unroll
        for (int k = 0; k < 4; ++k) {
            const int d = q4 * 4 + k;
            float xvv  = xb[(size_t)d * 2048];
            float diff = q[k] - xvv;               // quantized - inputs
            lsum = fmaf(diff, diff, lsum);
            ob[(size_t)d * 2048] = xvv + diff;     // exact STE forward rounding
        }
    }

    #pragma unroll
    for (int off = 32; off >= 1; off >>= 1) lsum += __shfl_xor(lsum, off);
    __shared__ float bsum[4];
    if ((tid & 63) == 0) bsum[tid >> 6] = lsum;
    __syncthreads();
    if (tid == 0) atomicAdd(loss_accum, bsum[0] + bsum[1] + bsum[2] + bsum[3]);
}

// ---------------------------------------------------------------- finalize scalars (tiny)
__global__ void vq_finalize(const float* __restrict__ loss_accum, const int* __restrict__ usage,
                            float* __restrict__ o_scalars)
{
    __shared__ int wsum[16];
    int tid = threadIdx.x;   // 1024 threads
    int c = (tid < KCODES && usage[tid]) ? 1 : 0;
    #pragma unroll
    for (int off = 32; off >= 1; off >>= 1) c += __shfl_xor(c, off);
    if ((tid & 63) == 0) wsum[tid >> 6] = c;
    __syncthreads();
    if (tid == 0) {
        int total = 0;
        #pragma unroll
        for (int i = 0; i < 16; ++i) total += wsum[i];
        float m = *loss_accum / 2097152.0f;        // mean over B*L*D
        o_scalars[0] = 11.0f * m;                  // q_latent + 10 * e_latent
        o_scalars[1] = (float)total;
    }
}

// ---------------------------------------------------------------- launch
extern "C" void kernel_launch(void* const* d_in, const int* in_sizes, int n_in,
                              void* d_out, int out_size, void* d_ws, size_t ws_size,
                              hipStream_t stream)
{
    const float* x   = (const float*)d_in[0];   // [16, 64, 2048]
    const float* emb = (const float*)d_in[1];   // [1000, 64]

    float* o       = (float*)d_out;
    float* out     = o;                 // 2097152 floats, [B, D, L]
    float* o_scal  = o + 2097152;       // loss, usage
    float* o_idx   = o + 2097154;       // 32768 floats

    char*  ws         = (char*)d_ws;
    float* loss_accum = (float*)(ws);
    int*   usage      = (int*)(ws + 64);
    float* pval       = (float*)(ws + 8192);
    int*   pidx       = (int*)(ws + 8192 + NSPLIT * NTOK * sizeof(float));
    // total ws use: ~1.06 MB

    vq_main<<<NSPLIT * 128, 256, 0, stream>>>(x, emb, pval, pidx, loss_accum, usage);
    vq_output<<<NTOK / 64, 256, 0, stream>>>(x, emb, pval, pidx, out, o_idx, loss_accum, usage);
    vq_finalize<<<1, 1024, 0, stream>>>(loss_accum, usage, o_scal);
}